// Round 5
// baseline (739.662 us; speedup 1.0000x reference)
//
#include <hip/hip_runtime.h>

#define H 512
#define OW 128
#define NB 16384

typedef float f32x4 __attribute__((ext_vector_type(4)));
typedef short short8 __attribute__((ext_vector_type(8)));
typedef unsigned short ushort8v __attribute__((ext_vector_type(8)));

static __device__ __forceinline__ unsigned short f2bf(float f) {
    union { float f; unsigned u; } v; v.f = f;
    return (unsigned short)((v.u + 0x7FFFu + ((v.u >> 16) & 1u)) >> 16);  // RNE
}

static __device__ __forceinline__ f32x4 mfma16(short8 a, short8 b, f32x4 c) {
    return __builtin_amdgcn_mfma_f32_16x16x32_bf16(a, b, c, 0, 0, 0);
}

// Async 16B/lane global->LDS DMA (linear LDS dest, pre-swizzled global src).
static __device__ __forceinline__ void gll16(const unsigned short* g, unsigned short* l) {
    __builtin_amdgcn_global_load_lds(
        (__attribute__((address_space(1))) void*)g,
        (__attribute__((address_space(3))) void*)l, 16, 0, 0);
}

// Swizzled LDS tile [rows][64 shorts]: 16B chunk ch of row r lives at phys
// chunk ch^(r&7). Conflict-free (verified SQ_LDS_BANK_CONFLICT ~= 0).
static __device__ __forceinline__ short8 sw_read(const unsigned short* l, int row, int ch) {
    return *(const short8*)&l[row * 64 + ((ch ^ (row & 7)) << 3)];
}

// ---- prep: weights transpose+cast, x cast (unchanged, proven) ----
__global__ void prep_w1(const float* __restrict__ share_W1,
                        const float* __restrict__ task_W1,
                        unsigned short* __restrict__ w1t) {
    const int inst = blockIdx.z;
    const float* src = (inst < 5) ? (share_W1 + (size_t)inst * H * H)
                                  : (task_W1 + (size_t)(inst - 5) * H * H);
    unsigned short* dst = w1t + (size_t)inst * H * H;
    const int g = blockIdx.x * 256 + threadIdx.x;
    const int n = g & (H - 1);
    const int kc = g >> 9;
    float v[8];
#pragma unroll
    for (int i = 0; i < 8; ++i) v[i] = src[(size_t)(kc * 8 + i) * H + n];
    ushort8v o;
#pragma unroll
    for (int i = 0; i < 8; ++i) o[i] = f2bf(v[i]);
    *(ushort8v*)&dst[(size_t)n * H + kc * 8] = o;
}

__global__ void prep_w2(const float* __restrict__ share_W2,
                        const float* __restrict__ task_W2,
                        unsigned short* __restrict__ w2t) {
    const int inst = blockIdx.z;
    const float* src = (inst < 5) ? (share_W2 + (size_t)inst * H * OW)
                                  : (task_W2 + (size_t)(inst - 5) * H * OW);
    unsigned short* dst = w2t + (size_t)inst * OW * H;
    const int g = blockIdx.x * 256 + threadIdx.x;
    const int n = g & (OW - 1);
    const int kc = g >> 7;
    float v[8];
#pragma unroll
    for (int i = 0; i < 8; ++i) v[i] = src[(size_t)(kc * 8 + i) * OW + n];
    ushort8v o;
#pragma unroll
    for (int i = 0; i < 8; ++i) o[i] = f2bf(v[i]);
    *(ushort8v*)&dst[(size_t)n * H + kc * 8] = o;
}

__global__ void prep_x(const float* __restrict__ x0, const float* __restrict__ x1,
                       const float* __restrict__ x2, unsigned short* __restrict__ xb) {
    const int z = blockIdx.z;
    const float* s = (z == 0) ? x0 : (z == 1 ? x1 : x2);
    const size_t g = (size_t)(blockIdx.x * 256 + threadIdx.x) * 8;
    float4 a = *(const float4*)&s[g];
    float4 b = *(const float4*)&s[g + 4];
    ushort8v o;
    o[0] = f2bf(a.x); o[1] = f2bf(a.y); o[2] = f2bf(a.z); o[3] = f2bf(a.w);
    o[4] = f2bf(b.x); o[5] = f2bf(b.y); o[6] = f2bf(b.z); o[7] = f2bf(b.w);
    *(ushort8v*)&xb[(size_t)z * NB * H + g] = o;
}

// ---- fused: out = relu(x@W1+b1)@W2 + b2, h never leaves LDS ----
// R3 structure (proven 203us, clean counters) + occupancy lever:
// sH shrunk to [128][72] (rows 144B = 9x16B: b128-aligned, row->row+1
// shifts 4 banks -> 2-way = free). gemm2 runs in two 64-col passes
// (pass p: wx==p waves write their h-cols into sH64, all waves MFMA
// against sW half p). LDS: sA 16K | sB 16K | sH64 18K = 50 KB ->
// 3 blocks/CU (was 2 at 67.6K). sW halves alias sA/sB after kt-loop.
__global__ __launch_bounds__(256, 3) void fused(
    const unsigned short* __restrict__ xb, const unsigned short* __restrict__ w1t,
    const unsigned short* __restrict__ w2t,
    const float* __restrict__ share_b1, const float* __restrict__ task_b1,
    const float* __restrict__ share_b2, const float* __restrict__ task_b2,
    float* __restrict__ out)
{
    __shared__ unsigned short smem[25600];      // 50 KB
    unsigned short* sA  = smem;                 // [128][64] swizzled (x)
    unsigned short* sB  = smem + 8192;          // [128][64] swizzled (W1 cols)
    unsigned short* sH  = smem + 16384;         // [128][72] bf16 h half-chunk
    unsigned short* sW0 = smem;                 // W2 k-half 0, aliases sA
    unsigned short* sW1 = smem + 8192;          // W2 k-half 1, aliases sB

    const int tid = threadIdx.x;
    const int lane = tid & 63;
    const int wave = tid >> 6;
    const int wy = wave >> 1, wx = wave & 1;
    const int lm = lane & 15, lq = lane >> 4;
    const int prow = lane >> 3;                 // 0..7: phys row within 8-row group
    const int lch  = (lane & 7) ^ prow;         // pre-swizzled source chunk

    // XCD-bijective swizzle: 1920 % 8 == 0; e fastest -> experts sharing an
    // x rowtile are L2-co-resident on one XCD.
    const int swz = (blockIdx.x & 7) * 240 + (blockIdx.x >> 3);
    const int z = swz / 640;
    const int rzi = swz % 640;
    const int rowtile = rzi / 5;
    const int e = rzi % 5;
    const int inst = z * 5 + e;

    const unsigned short* xp  = xb + ((size_t)z * NB + rowtile * 128) * H;
    const unsigned short* w1p = w1t + (size_t)inst * H * H;
    const unsigned short* w2p = w2t + (size_t)inst * OW * H;
    const float* b1 = (z == 0) ? (share_b1 + e * H) : (task_b1 + ((z - 1) * 5 + e) * H);
    const float* b2 = (z == 0) ? (share_b2 + e * OW) : (task_b2 + ((z - 1) * 5 + e) * OW);
    float* op = out + ((size_t)inst * NB + rowtile * 128) * OW;

    const f32x4 zero4 = {0.f, 0.f, 0.f, 0.f};
    f32x4 acc2[4][4];
#pragma unroll
    for (int i = 0; i < 4; ++i)
#pragma unroll
        for (int j = 0; j < 4; ++j) acc2[i][j] = zero4;

    for (int nt = 0; nt < 4; ++nt) {
        const unsigned short* wnp = w1p + (size_t)(nt * 128) * H;

        f32x4 acc1[4][4];
#pragma unroll
        for (int i = 0; i < 4; ++i)
#pragma unroll
            for (int j = 0; j < 4; ++j) acc1[i][j] = zero4;

        // ---- gemm1 chunk: h[128 rows][128 cols of nt] over K=512 ----
        for (int kt = 0; kt < 8; ++kt) {
            __syncthreads();                    // prev readers of sA/sB(/sW) done
#pragma unroll
            for (int t = 0; t < 4; ++t) {
                const int row = wave * 32 + t * 8 + prow;
                const int lo = wave * 2048 + t * 512;
                gll16(&xp [(size_t)row * H + kt * 64 + lch * 8], &sA[lo]);
                gll16(&wnp[(size_t)row * H + kt * 64 + lch * 8], &sB[lo]);
            }
            __syncthreads();                    // vmcnt(0) drain -> tiles ready
#pragma unroll
            for (int kk = 0; kk < 2; ++kk) {
                short8 af[4], bfr[4];
#pragma unroll
                for (int i = 0; i < 4; ++i) af[i] = sw_read(sA, wy * 64 + i * 16 + lm, kk * 4 + lq);
#pragma unroll
                for (int j = 0; j < 4; ++j) bfr[j] = sw_read(sB, wx * 64 + j * 16 + lm, kk * 4 + lq);
#pragma unroll
                for (int i = 0; i < 4; ++i)
#pragma unroll
                    for (int j = 0; j < 4; ++j) acc1[i][j] = mfma16(af[i], bfr[j], acc1[i][j]);
            }
        }
        __syncthreads();    // all sA/sB frag reads done before sW2 alias-DMA

        // ---- W2 chunk DMA (both k-halves); latency hides under pass-0 epilogue ----
#pragma unroll
        for (int t = 0; t < 4; ++t) {
            const int row = wave * 32 + t * 8 + prow;     // n index of W2^T
            const int lo = wave * 2048 + t * 512;
            gll16(&w2p[(size_t)row * H + nt * 128 +      lch * 8], &sW0[lo]);
            gll16(&w2p[(size_t)row * H + nt * 128 + 64 + lch * 8], &sW1[lo]);
        }

        // ---- two 64-col passes: epilogue-half -> gemm2-half ----
#pragma unroll
        for (int pass = 0; pass < 2; ++pass) {
            if (wx == pass) {                   // this wave's cols = pass half
#pragma unroll
                for (int j = 0; j < 4; ++j) {
                    const int col = j * 16 + lm;            // local col in half
                    const float b1v = b1[nt * 128 + pass * 64 + col];
#pragma unroll
                    for (int i = 0; i < 4; ++i)
#pragma unroll
                        for (int rr = 0; rr < 4; ++rr) {
                            const int row = wy * 64 + i * 16 + lq * 4 + rr;
                            sH[row * 72 + col] = f2bf(fmaxf(acc1[i][j][rr] + b1v, 0.f));
                        }
                }
            }
            __syncthreads();    // pass 0: also drains sW DMA (vmcnt 0)

            // gemm2 half: acc2 += h[:, pass*64..] @ W2[pass*64.., :]
            const unsigned short* sW = pass ? sW1 : sW0;
#pragma unroll
            for (int kk = 0; kk < 2; ++kk) {
                short8 ah[4], bfr[4];
#pragma unroll
                for (int i = 0; i < 4; ++i)
                    ah[i] = *(const short8*)&sH[(wy * 64 + i * 16 + lm) * 72 + kk * 32 + lq * 8];
#pragma unroll
                for (int j = 0; j < 4; ++j)
                    bfr[j] = sw_read(sW, wx * 64 + j * 16 + lm, kk * 4 + lq);
#pragma unroll
                for (int i = 0; i < 4; ++i)
#pragma unroll
                    for (int j = 0; j < 4; ++j) acc2[i][j] = mfma16(ah[i], bfr[j], acc2[i][j]);
            }
            if (pass == 0) __syncthreads();     // gemm2-p0 reads done before p1 rewrite
        }
    }

    // ---- final epilogue: out = acc2 + b2 (fp32) ----
#pragma unroll
    for (int j = 0; j < 4; ++j) {
        const int col = wx * 64 + j * 16 + lm;
        const float b2v = b2[col];
#pragma unroll
        for (int i = 0; i < 4; ++i)
#pragma unroll
            for (int rr = 0; rr < 4; ++rr) {
                const int row = wy * 64 + i * 16 + lq * 4 + rr;
                op[(size_t)row * OW + col] = acc2[i][j][rr] + b2v;
            }
    }
}

extern "C" void kernel_launch(void* const* d_in, const int* in_sizes, int n_in,
                              void* d_out, int out_size, void* d_ws, size_t ws_size,
                              hipStream_t stream) {
    const float* share_x  = (const float*)d_in[0];
    const float* task_x0  = (const float*)d_in[1];
    const float* task_x1  = (const float*)d_in[2];
    const float* share_W1 = (const float*)d_in[3];
    const float* share_b1 = (const float*)d_in[4];
    const float* share_W2 = (const float*)d_in[5];
    const float* share_b2 = (const float*)d_in[6];
    const float* task_W1  = (const float*)d_in[7];
    const float* task_b1  = (const float*)d_in[8];
    const float* task_W2  = (const float*)d_in[9];
    const float* task_b2  = (const float*)d_in[10];
    float* out = (float*)d_out;

    // ws layout (60.2 MB): w1t 7.86M | w2t 1.97M | xb 50.3M
    unsigned short* w1t = (unsigned short*)d_ws;
    unsigned short* w2t = w1t + (size_t)15 * H * H;
    unsigned short* xb  = w2t + (size_t)15 * OW * H;

    prep_w1<<<dim3(128, 1, 15), 256, 0, stream>>>(share_W1, task_W1, w1t);
    prep_w2<<<dim3(32, 1, 15), 256, 0, stream>>>(share_W2, task_W2, w2t);
    prep_x <<<dim3(4096, 1, 3), 256, 0, stream>>>(share_x, task_x0, task_x1, xb);
    fused<<<1920, 256, 0, stream>>>(xb, w1t, w2t, share_b1, task_b1,
                                    share_b2, task_b2, out);
}

// Round 6
// 412.249 us; speedup vs baseline: 1.7942x; 1.7942x over previous
//
#include <hip/hip_runtime.h>

#define H 512
#define OW 128
#define NB 16384

typedef float f32x4 __attribute__((ext_vector_type(4)));
typedef short short8 __attribute__((ext_vector_type(8)));
typedef unsigned short ushort8v __attribute__((ext_vector_type(8)));

static __device__ __forceinline__ unsigned short f2bf(float f) {
    union { float f; unsigned u; } v; v.f = f;
    return (unsigned short)((v.u + 0x7FFFu + ((v.u >> 16) & 1u)) >> 16);  // RNE
}

static __device__ __forceinline__ f32x4 mfma16(short8 a, short8 b, f32x4 c) {
    return __builtin_amdgcn_mfma_f32_16x16x32_bf16(a, b, c, 0, 0, 0);
}

// Async 16B/lane global->LDS DMA (linear LDS dest, pre-swizzled global src).
static __device__ __forceinline__ void gll16(const unsigned short* g, unsigned short* l) {
    __builtin_amdgcn_global_load_lds(
        (__attribute__((address_space(1))) void*)g,
        (__attribute__((address_space(3))) void*)l, 16, 0, 0);
}

// Swizzled LDS tile [rows][64 shorts]: 16B chunk ch of row r lives at phys
// chunk ch^(r&7). Conflict-free (verified SQ_LDS_BANK_CONFLICT ~= 0).
static __device__ __forceinline__ short8 sw_read(const unsigned short* l, int row, int ch) {
    return *(const short8*)&l[row * 64 + ((ch ^ (row & 7)) << 3)];
}

// ---- prep: weights transpose+cast, x cast (unchanged, proven) ----
__global__ void prep_w1(const float* __restrict__ share_W1,
                        const float* __restrict__ task_W1,
                        unsigned short* __restrict__ w1t) {
    const int inst = blockIdx.z;
    const float* src = (inst < 5) ? (share_W1 + (size_t)inst * H * H)
                                  : (task_W1 + (size_t)(inst - 5) * H * H);
    unsigned short* dst = w1t + (size_t)inst * H * H;
    const int g = blockIdx.x * 256 + threadIdx.x;
    const int n = g & (H - 1);
    const int kc = g >> 9;
    float v[8];
#pragma unroll
    for (int i = 0; i < 8; ++i) v[i] = src[(size_t)(kc * 8 + i) * H + n];
    ushort8v o;
#pragma unroll
    for (int i = 0; i < 8; ++i) o[i] = f2bf(v[i]);
    *(ushort8v*)&dst[(size_t)n * H + kc * 8] = o;
}

__global__ void prep_w2(const float* __restrict__ share_W2,
                        const float* __restrict__ task_W2,
                        unsigned short* __restrict__ w2t) {
    const int inst = blockIdx.z;
    const float* src = (inst < 5) ? (share_W2 + (size_t)inst * H * OW)
                                  : (task_W2 + (size_t)(inst - 5) * H * OW);
    unsigned short* dst = w2t + (size_t)inst * OW * H;
    const int g = blockIdx.x * 256 + threadIdx.x;
    const int n = g & (OW - 1);
    const int kc = g >> 7;
    float v[8];
#pragma unroll
    for (int i = 0; i < 8; ++i) v[i] = src[(size_t)(kc * 8 + i) * OW + n];
    ushort8v o;
#pragma unroll
    for (int i = 0; i < 8; ++i) o[i] = f2bf(v[i]);
    *(ushort8v*)&dst[(size_t)n * H + kc * 8] = o;
}

__global__ void prep_x(const float* __restrict__ x0, const float* __restrict__ x1,
                       const float* __restrict__ x2, unsigned short* __restrict__ xb) {
    const int z = blockIdx.z;
    const float* s = (z == 0) ? x0 : (z == 1 ? x1 : x2);
    const size_t g = (size_t)(blockIdx.x * 256 + threadIdx.x) * 8;
    float4 a = *(const float4*)&s[g];
    float4 b = *(const float4*)&s[g + 4];
    ushort8v o;
    o[0] = f2bf(a.x); o[1] = f2bf(a.y); o[2] = f2bf(a.z); o[3] = f2bf(a.w);
    o[4] = f2bf(b.x); o[5] = f2bf(b.y); o[6] = f2bf(b.z); o[7] = f2bf(b.w);
    *(ushort8v*)&xb[(size_t)z * NB * H + g] = o;
}

// ---- fused: out = relu(x@W1+b1)@W2 + b2, h never leaves LDS ----
// R3 memory structure (proven: FETCH 82MB, conflicts ~0, fused 203us),
// re-decomposed to 512 threads / 8 waves (4 row-groups x 2 col-groups):
// per-wave tile 32x64 -> acc1[2][4]+acc2[2][4] = 64 regs, fits the 128-reg
// cap of 4 waves/SIMD (launch_bounds(512,4); R5 lesson: 256-thread 4x4+4x4
// accs at 3 blk/CU spills -> 690MB scratch writes). LDS unchanged 67.6KB ->
// 2 blocks/CU = 16 waves/CU (2x R3's latency hiding for the vmcnt(0)
// barrier drains). All swizzles/DMA byte-identical to R3.
__global__ __launch_bounds__(512, 4) void fused(
    const unsigned short* __restrict__ xb, const unsigned short* __restrict__ w1t,
    const unsigned short* __restrict__ w2t,
    const float* __restrict__ share_b1, const float* __restrict__ task_b1,
    const float* __restrict__ share_b2, const float* __restrict__ task_b2,
    float* __restrict__ out)
{
    __shared__ unsigned short smem[33792];      // 67.6 KB
    unsigned short* sA  = smem;                 // [128][64] swizzled (x)
    unsigned short* sB  = smem + 8192;          // [128][64] swizzled (W1 cols)
    unsigned short* sH  = smem + 16384;         // [128][136] bf16 h_chunk
    unsigned short* sW0 = smem;                 // W2 k-half 0, aliases sA
    unsigned short* sW1 = smem + 8192;          // W2 k-half 1, aliases sB

    const int tid = threadIdx.x;
    const int lane = tid & 63;
    const int wave = tid >> 6;                  // 0..7
    const int wy = wave >> 1, wx = wave & 1;    // wy 0..3 (rows), wx 0..1 (cols)
    const int lm = lane & 15, lq = lane >> 4;
    const int prow = lane >> 3;                 // 0..7: phys row within 8-row group
    const int lch  = (lane & 7) ^ prow;         // pre-swizzled source chunk

    // XCD-bijective swizzle: 1920 % 8 == 0; e fastest -> experts sharing an
    // x rowtile are L2-co-resident on one XCD.
    const int swz = (blockIdx.x & 7) * 240 + (blockIdx.x >> 3);
    const int z = swz / 640;
    const int rzi = swz % 640;
    const int rowtile = rzi / 5;
    const int e = rzi % 5;
    const int inst = z * 5 + e;

    const unsigned short* xp  = xb + ((size_t)z * NB + rowtile * 128) * H;
    const unsigned short* w1p = w1t + (size_t)inst * H * H;
    const unsigned short* w2p = w2t + (size_t)inst * OW * H;
    const float* b1 = (z == 0) ? (share_b1 + e * H) : (task_b1 + ((z - 1) * 5 + e) * H);
    const float* b2 = (z == 0) ? (share_b2 + e * OW) : (task_b2 + ((z - 1) * 5 + e) * OW);
    float* op = out + ((size_t)inst * NB + rowtile * 128) * OW;

    const f32x4 zero4 = {0.f, 0.f, 0.f, 0.f};
    f32x4 acc2[2][4];
#pragma unroll
    for (int i = 0; i < 2; ++i)
#pragma unroll
        for (int j = 0; j < 4; ++j) acc2[i][j] = zero4;

    for (int nt = 0; nt < 4; ++nt) {
        const unsigned short* wnp = w1p + (size_t)(nt * 128) * H;

        f32x4 acc1[2][4];
#pragma unroll
        for (int i = 0; i < 2; ++i)
#pragma unroll
            for (int j = 0; j < 4; ++j) acc1[i][j] = zero4;

        // ---- gemm1 chunk: h[128 rows][128 cols of nt] over K=512 ----
        for (int kt = 0; kt < 8; ++kt) {
            __syncthreads();                    // prev readers of sA/sB(/sW) done
#pragma unroll
            for (int t = 0; t < 2; ++t) {
                const int row = wave * 16 + t * 8 + prow;
                const int lo = wave * 1024 + t * 512;
                gll16(&xp [(size_t)row * H + kt * 64 + lch * 8], &sA[lo]);
                gll16(&wnp[(size_t)row * H + kt * 64 + lch * 8], &sB[lo]);
            }
            __syncthreads();                    // vmcnt(0) drain -> tiles ready
#pragma unroll
            for (int kk = 0; kk < 2; ++kk) {
                short8 af[2], bfr[4];
#pragma unroll
                for (int i = 0; i < 2; ++i) af[i] = sw_read(sA, wy * 32 + i * 16 + lm, kk * 4 + lq);
#pragma unroll
                for (int j = 0; j < 4; ++j) bfr[j] = sw_read(sB, wx * 64 + j * 16 + lm, kk * 4 + lq);
#pragma unroll
                for (int i = 0; i < 2; ++i)
#pragma unroll
                    for (int j = 0; j < 4; ++j) acc1[i][j] = mfma16(af[i], bfr[j], acc1[i][j]);
            }
        }
        __syncthreads();    // all sA/sB frag reads done before sW2 alias-DMA

        // ---- W2 chunk DMA into swizzled halves (latency hides under epilogue) ----
#pragma unroll
        for (int t = 0; t < 2; ++t) {
            const int row = wave * 16 + t * 8 + prow;     // n index of W2^T
            const int lo = wave * 1024 + t * 512;
            gll16(&w2p[(size_t)row * H + nt * 128 +      lch * 8], &sW0[lo]);
            gll16(&w2p[(size_t)row * H + nt * 128 + 64 + lch * 8], &sW1[lo]);
        }

        // ---- epilogue gemm1: +b1, relu, bf16 -> sH[128][136] ----
#pragma unroll
        for (int j = 0; j < 4; ++j) {
            const int col = wx * 64 + j * 16 + lm;
            const float b1v = b1[nt * 128 + col];
#pragma unroll
            for (int i = 0; i < 2; ++i)
#pragma unroll
                for (int rr = 0; rr < 4; ++rr) {
                    const int row = wy * 32 + i * 16 + lq * 4 + rr;
                    sH[row * 136 + col] = f2bf(fmaxf(acc1[i][j][rr] + b1v, 0.f));
                }
        }
        __syncthreads();    // vmcnt(0) drain: sW ready; sH writes visible

        // ---- gemm2 accumulate: acc2 += h_chunk @ W2_chunk (k=128) ----
#pragma unroll
        for (int kk = 0; kk < 4; ++kk) {
            short8 ah[2], bfr[4];
#pragma unroll
            for (int i = 0; i < 2; ++i)
                ah[i] = *(const short8*)&sH[(wy * 32 + i * 16 + lm) * 136 + kk * 32 + lq * 8];
#pragma unroll
            for (int j = 0; j < 4; ++j)
                bfr[j] = sw_read((kk & 2) ? sW1 : sW0, wx * 64 + j * 16 + lm, (kk & 1) * 4 + lq);
#pragma unroll
            for (int i = 0; i < 2; ++i)
#pragma unroll
                for (int j = 0; j < 4; ++j) acc2[i][j] = mfma16(ah[i], bfr[j], acc2[i][j]);
        }
    }

    // ---- final epilogue: out = acc2 + b2 (fp32) ----
#pragma unroll
    for (int j = 0; j < 4; ++j) {
        const int col = wx * 64 + j * 16 + lm;
        const float b2v = b2[col];
#pragma unroll
        for (int i = 0; i < 2; ++i)
#pragma unroll
            for (int rr = 0; rr < 4; ++rr) {
                const int row = wy * 32 + i * 16 + lq * 4 + rr;
                op[(size_t)row * OW + col] = acc2[i][j][rr] + b2v;
            }
    }
}

extern "C" void kernel_launch(void* const* d_in, const int* in_sizes, int n_in,
                              void* d_out, int out_size, void* d_ws, size_t ws_size,
                              hipStream_t stream) {
    const float* share_x  = (const float*)d_in[0];
    const float* task_x0  = (const float*)d_in[1];
    const float* task_x1  = (const float*)d_in[2];
    const float* share_W1 = (const float*)d_in[3];
    const float* share_b1 = (const float*)d_in[4];
    const float* share_W2 = (const float*)d_in[5];
    const float* share_b2 = (const float*)d_in[6];
    const float* task_W1  = (const float*)d_in[7];
    const float* task_b1  = (const float*)d_in[8];
    const float* task_W2  = (const float*)d_in[9];
    const float* task_b2  = (const float*)d_in[10];
    float* out = (float*)d_out;

    // ws layout (60.2 MB): w1t 7.86M | w2t 1.97M | xb 50.3M
    unsigned short* w1t = (unsigned short*)d_ws;
    unsigned short* w2t = w1t + (size_t)15 * H * H;
    unsigned short* xb  = w2t + (size_t)15 * OW * H;

    prep_w1<<<dim3(128, 1, 15), 256, 0, stream>>>(share_W1, task_W1, w1t);
    prep_w2<<<dim3(32, 1, 15), 256, 0, stream>>>(share_W2, task_W2, w2t);
    prep_x <<<dim3(4096, 1, 3), 256, 0, stream>>>(share_x, task_x0, task_x1, xb);
    fused<<<1920, 512, 0, stream>>>(xb, w1t, w2t, share_b1, task_b1,
                                    share_b2, task_b2, out);
}